// Round 10
// baseline (541.309 us; speedup 1.0000x reference)
//
#include <hip/hip_runtime.h>

namespace {

constexpr int Bn = 4;
constexpr int C  = 192;
constexpr int Wd = 128;
constexpr int HW = 16384;            // 128*128
constexpr int PLANE = Bn * C * HW;   // 12582912
constexpr int NH = 6;
constexpr int HD = 32;
constexpr int C4 = 4 * C;            // 768
constexpr float SCALE = 0.17677669529663687f;  // 32^-0.5

// packed bf16 weight layout in d_ws (short offsets)
constexpr int OQKV_R = 0;            // 576*192
constexpr int OQKV_I = 110592;
constexpr int OPROJ_R = 221184;      // 192*192
constexpr int OPROJ_I = 258048;
constexpr int OW1_R = 294912;        // 768*192
constexpr int OW1_I = 442368;
constexpr int OW2_R = 589824;        // 192*768
constexpr int OW2_I = 737280;
constexpr int PK_TOTAL = 884736;
constexpr int ZS = 8;                // stats split factor

typedef short bf16x8 __attribute__((ext_vector_type(8)));
typedef float f32x4 __attribute__((ext_vector_type(4)));

__device__ inline unsigned short f2bf(float f) {
  union { float f; unsigned u; } v; v.f = f;
  const unsigned r = v.u + 0x7FFFu + ((v.u >> 16) & 1u);
  return (unsigned short)(r >> 16);
}

__device__ inline float bf2f(short s) {
  union { unsigned u; float f; } v;
  v.u = ((unsigned)(unsigned short)s) << 16;
  return v.f;
}

__device__ inline bf16x8 pack8(const float* f) {
  union { bf16x8 v; unsigned short s[8]; } x;
#pragma unroll
  for (int j = 0; j < 8; ++j) x.s[j] = f2bf(f[j]);
  return x.v;
}

__device__ inline uint2 pack4(const f32x4 v) {
  return make_uint2((unsigned)f2bf(v[0]) | ((unsigned)f2bf(v[1]) << 16),
                    (unsigned)f2bf(v[2]) | ((unsigned)f2bf(v[3]) << 16));
}

__device__ inline bf16x8 negb(bf16x8 a) {
  union { bf16x8 v; unsigned u[4]; } x;
  x.v = a;
#pragma unroll
  for (int j = 0; j < 4; ++j) x.u[j] ^= 0x80008000u;
  return x.v;
}

// Phi(m) = 0.5(1+erf(m/sqrt2)), m>=0. Abramowitz-Stegun 7.1.26, |err|<1.5e-7.
__device__ inline float phi_gelu(float m) {
  const float x = m * 0.70710678f;
  const float tt = 1.0f / (1.0f + 0.3275911f * x);
  const float poly = tt * (0.254829592f + tt * (-0.284496736f +
                     tt * (1.421413741f + tt * (-1.453152027f + tt * 1.061405429f))));
  return 1.0f - 0.5f * poly * __expf(-x * x);
}

// ---------------------------------------------------------------------------
// Pack all weights to bf16 into ws (one pass, ~900K elements).
// ---------------------------------------------------------------------------
__global__ __launch_bounds__(256) void k_pack(
    const float* __restrict__ s0, const float* __restrict__ s1,
    const float* __restrict__ s2, const float* __restrict__ s3,
    const float* __restrict__ s4, const float* __restrict__ s5,
    const float* __restrict__ s6, const float* __restrict__ s7,
    short* __restrict__ dst)
{
  for (int i = blockIdx.x * 256 + threadIdx.x; i < PK_TOTAL; i += gridDim.x * 256) {
    const float* s; int off;
    if (i < OPROJ_R) {
      if (i < OQKV_I) { s = s0; off = i; } else { s = s1; off = i - OQKV_I; }
    } else if (i < OW1_R) {
      if (i < OPROJ_I) { s = s2; off = i - OPROJ_R; } else { s = s3; off = i - OPROJ_I; }
    } else if (i < OW2_R) {
      if (i < OW1_I) { s = s4; off = i - OW1_R; } else { s = s5; off = i - OW1_I; }
    } else {
      if (i < OW2_I) { s = s6; off = i - OW2_R; } else { s = s7; off = i - OW2_I; }
    }
    dst[i] = (short)f2bf(s[off]);
  }
}

// ---------------------------------------------------------------------------
// Stage 1 (MFMA): windowed complex attention + proj + residual -> y in d_out.
// Block = 2 windows (64 px), 768 threads (12 waves). (unchanged from R7/R8)
// ---------------------------------------------------------------------------
template <bool PK>
__global__ __launch_bounds__(768) void k_attn(
    const float* __restrict__ xr, const float* __restrict__ xi,
    const float* __restrict__ wqkv_r, const float* __restrict__ wqkv_i,
    const float* __restrict__ wp_r, const float* __restrict__ wp_i,
    const short* __restrict__ wpk,
    const float* __restrict__ rpb,
    float* __restrict__ yr, float* __restrict__ yi)
{
  __shared__ short sX[2][64 * 192];   // x window bf16 [px][c^s]
  __shared__ short sQ[2][64 * 64];    // q head-pair [px][cc^s]
  __shared__ short sK[2][64 * 64];    // k head-pair [px][cc^s]
  __shared__ short sV[2][64 * 64];    // v head-pair [cc][px^s]
  __shared__ short sAO[2][64 * 64];   // attn-out head-pair [px][cc^s]
  __shared__ short sAT[2][4][1024];   // attn weights per task [n][m^s]
  __shared__ float sB[640];           // rpb table

  const int t = threadIdx.x;
  const int b = blockIdx.x >> 8;
  const int rem = blockIdx.x & 255;
  const int r0 = (rem >> 4) << 3;
  const int c0 = (rem & 15) << 3;     // two 4-wide windows: c0, c0+4
  const int gbase = b * C * HW + r0 * Wd + c0;

  #pragma unroll
  for (int it = 0; it < 4; ++it) {
    const int idx = t + it * 768;          // 0..3071
    const int c = idx >> 4;
    const int q4 = (idx & 15) << 2;        // px base, mult of 4
    const int wvs = q4 >> 5;
    const int row = (q4 & 31) >> 2;
    const int goff = gbase + c * HW + row * Wd + wvs * 4;
    const float4 vr = *(const float4*)(xr + goff);
    const float4 vi = *(const float4*)(xi + goff);
    const float fr[4] = {vr.x, vr.y, vr.z, vr.w};
    const float fi[4] = {vi.x, vi.y, vi.z, vi.w};
    #pragma unroll
    for (int j = 0; j < 4; ++j) {
      const int p = q4 + j;
      const int s = (p & 7) << 3;
      sX[0][p * 192 + (c ^ s)] = (short)f2bf(fr[j]);
      sX[1][p * 192 + (c ^ s)] = (short)f2bf(fi[j]);
    }
  }
  for (int i = t; i < 630; i += 768) sB[i] = rpb[i];
  __syncthreads();

  const int lane = t & 63;
  const int w = t >> 6;           // 0..11
  const int lr = lane & 15;
  const int lg = lane >> 4;

  f32x4 apr[4] = {}, api[4] = {};   // proj accumulators (persist; rows w*16)

  for (int g = 0; g < 3; ++g) {
    // ======== QKV GEMM: 192 rows (q64,k64,v64 of head pair) x 64 px ========
    {
      const int lrow = w * 16;             // 0..176
      const int sec = lrow >> 6;           // 0=q 1=k 2=v
      const int ccb = lrow & 63;
      const int R = sec * 192 + g * 64 + ccb + lr;
      f32x4 dr[4] = {}, di[4] = {};
      #pragma unroll
      for (int ks = 0; ks < 6; ++ks) {
        const int k8 = ks * 32 + lg * 8;
        bf16x8 ar, ai;
        if constexpr (PK) {
          ar = *(const bf16x8*)(wpk + OQKV_R + (size_t)R * C + k8);
          ai = *(const bf16x8*)(wpk + OQKV_I + (size_t)R * C + k8);
        } else {
          const float* wrp = wqkv_r + (size_t)R * C;
          const float* wip = wqkv_i + (size_t)R * C;
          float a[8];
          *(float4*)&a[0] = *(const float4*)(wrp + k8);
          *(float4*)&a[4] = *(const float4*)(wrp + k8 + 4);
          ar = pack8(a);
          *(float4*)&a[0] = *(const float4*)(wip + k8);
          *(float4*)&a[4] = *(const float4*)(wip + k8 + 4);
          ai = pack8(a);
        }
        const bf16x8 ain = negb(ai);
        #pragma unroll
        for (int cb = 0; cb < 4; ++cb) {
          const int px = cb * 16 + lr;
          const int s = (px & 7) << 3;
          const bf16x8 br = *(const bf16x8*)&sX[0][px * 192 + (k8 ^ s)];
          const bf16x8 bi = *(const bf16x8*)&sX[1][px * 192 + (k8 ^ s)];
          dr[cb] = __builtin_amdgcn_mfma_f32_16x16x32_bf16(ar,  br, dr[cb], 0, 0, 0);
          dr[cb] = __builtin_amdgcn_mfma_f32_16x16x32_bf16(ain, bi, dr[cb], 0, 0, 0);
          di[cb] = __builtin_amdgcn_mfma_f32_16x16x32_bf16(ar,  bi, di[cb], 0, 0, 0);
          di[cb] = __builtin_amdgcn_mfma_f32_16x16x32_bf16(ai,  br, di[cb], 0, 0, 0);
        }
      }
      if (sec < 2) {
        short* d0 = sec ? sK[0] : sQ[0];
        short* d1 = sec ? sK[1] : sQ[1];
        #pragma unroll
        for (int cb = 0; cb < 4; ++cb) {
          const int px = cb * 16 + lr;
          const int e = px * 64 + ((ccb + lg * 4) ^ ((px & 7) << 3));
          *(uint2*)&d0[e] = pack4(dr[cb]);
          *(uint2*)&d1[e] = pack4(di[cb]);
        }
      } else {
        #pragma unroll
        for (int cb = 0; cb < 4; ++cb) {
          const int px = cb * 16 + lr;
          #pragma unroll
          for (int r = 0; r < 4; ++r) {
            const int dd = ccb + lg * 4 + r;
            const int e = dd * 64 + (px ^ ((dd & 7) << 3));
            sV[0][e] = (short)f2bf(dr[cb][r]);
            sV[1][e] = (short)f2bf(di[cb][r]);
          }
        }
      }
    }
    __syncthreads();   // bar A: qkv visible

    // ======== attention: waves 0..7 = (task, half); waves 8..11 idle ========
    if (w < 8) {
      const int task = w >> 1;
      const int half = w & 1;
      const int hloc = task >> 1;
      const int wv = task & 1;
      const int ccq = hloc * 32;
      const int h = 2 * g + hloc;
      bf16x8 aqr, aqi, bkr[2], bki[2];
      {
        const int pxq = wv * 32 + half * 16 + lr;
        const int eq = pxq * 64 + ((ccq + lg * 8) ^ ((pxq & 7) << 3));
        aqr = *(const bf16x8*)&sQ[0][eq];
        aqi = *(const bf16x8*)&sQ[1][eq];
      }
      #pragma unroll
      for (int j = 0; j < 2; ++j) {
        const int pxk = wv * 32 + j * 16 + lr;
        const int ek = pxk * 64 + ((ccq + lg * 8) ^ ((pxk & 7) << 3));
        bkr[j] = *(const bf16x8*)&sK[0][ek];
        bki[j] = *(const bf16x8*)&sK[1][ek];
      }
      f32x4 sre[2], sim[2];
      #pragma unroll
      for (int j = 0; j < 2; ++j) {
        f32x4 z = {};
        f32x4 re = __builtin_amdgcn_mfma_f32_16x16x32_bf16(aqr, bkr[j], z, 0, 0, 0);
        re = __builtin_amdgcn_mfma_f32_16x16x32_bf16(aqi, bki[j], re, 0, 0, 0);
        f32x4 im = __builtin_amdgcn_mfma_f32_16x16x32_bf16(aqi, bkr[j], z, 0, 0, 0);
        im = __builtin_amdgcn_mfma_f32_16x16x32_bf16(negb(aqr), bki[j], im, 0, 0, 0);
        sre[j] = re;
        sim[j] = im;
      }
      float re_[2][4], im_[2][4], mg_[2][4];
      #pragma unroll
      for (int j = 0; j < 2; ++j) {
        const int m = j * 16 + lr;
        #pragma unroll
        for (int r = 0; r < 4; ++r) {
          const int n = half * 16 + lg * 4 + r;
          const int bidx = ((n >> 2) - (m >> 2) + 7) * 7 + ((n & 3) - (m & 3) + 3);
          const float re = sre[j][r] * SCALE + sB[bidx * NH + h];
          const float im = sim[j][r] * SCALE;
          re_[j][r] = re;
          im_[j][r] = im;
          mg_[j][r] = sqrtf(re * re + im * im);
        }
      }
      #pragma unroll
      for (int r = 0; r < 4; ++r) {
        float mx = fmaxf(mg_[0][r], mg_[1][r]);
        mx = fmaxf(mx, __shfl_xor(mx, 1));
        mx = fmaxf(mx, __shfl_xor(mx, 2));
        mx = fmaxf(mx, __shfl_xor(mx, 4));
        mx = fmaxf(mx, __shfl_xor(mx, 8));
        const float e0 = expf(mg_[0][r] - mx);
        const float e1 = expf(mg_[1][r] - mx);
        float se = e0 + e1;
        se += __shfl_xor(se, 1);
        se += __shfl_xor(se, 2);
        se += __shfl_xor(se, 4);
        se += __shfl_xor(se, 8);
        const float inv = 1.f / se;
        const float f0 = e0 * inv / (mg_[0][r] + 1e-8f);
        const float f1 = e1 * inv / (mg_[1][r] + 1e-8f);
        const int n = half * 16 + lg * 4 + r;
        const int sw = (n & 3) << 3;
        sAT[0][task][n * 32 + (lr ^ sw)]        = (short)f2bf(re_[0][r] * f0);
        sAT[1][task][n * 32 + (lr ^ sw)]        = (short)f2bf(im_[0][r] * f0);
        sAT[0][task][n * 32 + ((16 + lr) ^ sw)] = (short)f2bf(re_[1][r] * f1);
        sAT[1][task][n * 32 + ((16 + lr) ^ sw)] = (short)f2bf(im_[1][r] * f1);
      }
      bf16x8 bar_, bai_;
      {
        const int n = half * 16 + lr;
        const int e = n * 32 + ((lg * 8) ^ ((n & 3) << 3));
        bar_ = *(const bf16x8*)&sAT[0][task][e];
        bai_ = *(const bf16x8*)&sAT[1][task][e];
      }
      #pragma unroll
      for (int i2 = 0; i2 < 2; ++i2) {
        const int dd = ccq + i2 * 16 + lr;
        const int e = dd * 64 + ((wv * 32 + lg * 8) ^ ((dd & 7) << 3));
        const bf16x8 avr = *(const bf16x8*)&sV[0][e];
        const bf16x8 avi = *(const bf16x8*)&sV[1][e];
        const bf16x8 avin = negb(avi);
        f32x4 z = {};
        f32x4 pr = __builtin_amdgcn_mfma_f32_16x16x32_bf16(avr, bar_, z, 0, 0, 0);
        pr = __builtin_amdgcn_mfma_f32_16x16x32_bf16(avin, bai_, pr, 0, 0, 0);
        f32x4 pi = __builtin_amdgcn_mfma_f32_16x16x32_bf16(avr, bai_, z, 0, 0, 0);
        pi = __builtin_amdgcn_mfma_f32_16x16x32_bf16(avi, bar_, pi, 0, 0, 0);
        const int px = wv * 32 + half * 16 + lr;
        const int e2 = px * 64 + ((ccq + i2 * 16 + lg * 4) ^ ((px & 7) << 3));
        *(uint2*)&sAO[0][e2] = pack4(pr);
        *(uint2*)&sAO[1][e2] = pack4(pi);
      }
    }

    // prefetch proj A-frags so their latency lands in bar B's drain (PK path)
    const int o = w * 16 + lr;
    bf16x8 ppr[2], ppi[2];
    if constexpr (PK) {
      #pragma unroll
      for (int ks = 0; ks < 2; ++ks) {
        const int k8 = ks * 32 + lg * 8;
        ppr[ks] = *(const bf16x8*)(wpk + OPROJ_R + (size_t)o * C + g * 64 + k8);
        ppi[ks] = *(const bf16x8*)(wpk + OPROJ_I + (size_t)o * C + g * 64 + k8);
      }
    }
    __syncthreads();   // bar B: attn-out visible

    // ======== proj accumulation: K = 64 (head pair), rows w*16 ========
    #pragma unroll
    for (int ks = 0; ks < 2; ++ks) {
      const int k8 = ks * 32 + lg * 8;
      bf16x8 pbr[4], pbi[4];
      #pragma unroll
      for (int cb = 0; cb < 4; ++cb) {
        const int px = cb * 16 + lr;
        const int e = px * 64 + (k8 ^ ((px & 7) << 3));
        pbr[cb] = *(const bf16x8*)&sAO[0][e];
        pbi[cb] = *(const bf16x8*)&sAO[1][e];
      }
      bf16x8 ar, ai;
      if constexpr (PK) {
        ar = ppr[ks];
        ai = ppi[ks];
      } else {
        const size_t wb = (size_t)o * C + g * 64 + k8;
        float a[8];
        *(float4*)&a[0] = *(const float4*)(wp_r + wb);
        *(float4*)&a[4] = *(const float4*)(wp_r + wb + 4);
        ar = pack8(a);
        *(float4*)&a[0] = *(const float4*)(wp_i + wb);
        *(float4*)&a[4] = *(const float4*)(wp_i + wb + 4);
        ai = pack8(a);
      }
      const bf16x8 ain = negb(ai);
      #pragma unroll
      for (int cb = 0; cb < 4; ++cb) {
        apr[cb] = __builtin_amdgcn_mfma_f32_16x16x32_bf16(ar,  pbr[cb], apr[cb], 0, 0, 0);
        apr[cb] = __builtin_amdgcn_mfma_f32_16x16x32_bf16(ain, pbi[cb], apr[cb], 0, 0, 0);
        api[cb] = __builtin_amdgcn_mfma_f32_16x16x32_bf16(ar,  pbi[cb], api[cb], 0, 0, 0);
        api[cb] = __builtin_amdgcn_mfma_f32_16x16x32_bf16(ai,  pbr[cb], api[cb], 0, 0, 0);
      }
    }
  }

  // ======== epilogue: y = x + proj_out (residual from sX, bf16) ========
  #pragma unroll
  for (int cb = 0; cb < 4; ++cb) {
    const int px = cb * 16 + lr;
    const int n = px & 31;
    const int off0 = gbase + (n >> 2) * Wd + (px >> 5) * 4 + (n & 3);
    const int s = (px & 7) << 3;
    #pragma unroll
    for (int r = 0; r < 4; ++r) {
      const int c = w * 16 + lg * 4 + r;
      const size_t gg = (size_t)off0 + (size_t)c * HW;
      yr[gg] = bf2f(sX[0][px * 192 + (c ^ s)]) + apr[cb][r];
      yi[gg] = bf2f(sX[1][px * 192 + (c ^ s)]) + api[cb][r];
    }
  }
}

// ---------------------------------------------------------------------------
// Split BN stats: grid (C, 2, ZS). Deterministic partials (no atomics).
// ---------------------------------------------------------------------------
__global__ __launch_bounds__(256) void k_statsp(
    const float* __restrict__ src_r, const float* __restrict__ src_i,
    double* __restrict__ part)
{
  const int c = blockIdx.x;
  const int plane = blockIdx.y;
  const int z = blockIdx.z;
  const float* src = plane ? src_i : src_r;
  const int t = threadIdx.x;
  double s = 0.0, s2 = 0.0;
  for (int b = 0; b < Bn; ++b) {
    const float* p = src + (size_t)(b * C + c) * HW + (size_t)z * (HW / ZS);
    #pragma unroll
    for (int it = 0; it < 2; ++it) {
      const float4 v = *(const float4*)(p + t * 4 + it * 1024);
      s += (double)v.x + (double)v.y + (double)v.z + (double)v.w;
      s2 += (double)v.x * v.x + (double)v.y * v.y +
            (double)v.z * v.z + (double)v.w * v.w;
    }
  }
  __shared__ double ls[256], ls2[256];
  ls[t] = s; ls2[t] = s2;
  __syncthreads();
  for (int off = 128; off > 0; off >>= 1) {
    if (t < off) { ls[t] += ls[t + off]; ls2[t] += ls2[t + off]; }
    __syncthreads();
  }
  if (t == 0) {
    const int e = ((z * 2 + plane) * C + c) * 2;
    part[e] = ls[0];
    part[e + 1] = ls2[0];
  }
}

// Reduce partials -> folded BN scale/shift. grid 2 x 192.
__global__ void k_bnpar2(const double* __restrict__ part,
                         const float* __restrict__ g_r, const float* __restrict__ b_r,
                         const float* __restrict__ g_i, const float* __restrict__ b_i,
                         float* __restrict__ sc, float* __restrict__ sh)
{
  const int plane = blockIdx.x;
  const int c = threadIdx.x;
  double s = 0.0, s2 = 0.0;
  #pragma unroll
  for (int z = 0; z < ZS; ++z) {
    const int e = ((z * 2 + plane) * C + c) * 2;
    s += part[e];
    s2 += part[e + 1];
  }
  const double inv = 1.0 / (double)(Bn * HW);
  const double m = s * inv;
  const double var = s2 * inv - m * m;
  const double rstd = 1.0 / sqrt(var + 1e-5);
  const float g = plane ? g_i[c] : g_r[c];
  const float bb = plane ? b_i[c] : b_r[c];
  const float sf = (float)(rstd) * g;
  sc[plane * C + c] = sf;
  sh[plane * C + c] = bb - (float)m * sf;
}

// ---------------------------------------------------------------------------
// Legacy monolithic stats (fallback when ws too small for partials).
// ---------------------------------------------------------------------------
__global__ __launch_bounds__(256) void k_stats(
    const float* __restrict__ src_r, const float* __restrict__ src_i,
    float* __restrict__ mean, float* __restrict__ rstd)
{
  const int c = blockIdx.x;
  const int plane = blockIdx.y;
  const float* src = plane ? src_i : src_r;
  const int t = threadIdx.x;
  double s = 0.0, s2 = 0.0;
  for (int b = 0; b < Bn; ++b) {
    const float* p = src + (size_t)(b * C + c) * HW;
    for (int i = t; i < HW; i += 256) {
      const double v = (double)p[i];
      s += v;
      s2 += v * v;
    }
  }
  __shared__ double ls[256], ls2[256];
  ls[t] = s; ls2[t] = s2;
  __syncthreads();
  for (int off = 128; off > 0; off >>= 1) {
    if (t < off) { ls[t] += ls[t + off]; ls2[t] += ls2[t + off]; }
    __syncthreads();
  }
  if (t == 0) {
    const double inv = 1.0 / (double)(Bn * HW);
    const double m = ls[0] * inv;
    const double var = ls2[0] * inv - m * m;
    mean[plane * C + c] = (float)m;
    rstd[plane * C + c] = (float)(1.0 / sqrt(var + 1e-5));
  }
}

__global__ void k_bnpar(const float* __restrict__ mean, const float* __restrict__ rstd,
                        const float* __restrict__ g_r, const float* __restrict__ b_r,
                        const float* __restrict__ g_i, const float* __restrict__ b_i,
                        float* __restrict__ sc, float* __restrict__ sh)
{
  const int i = blockIdx.x * blockDim.x + threadIdx.x;
  if (i >= 2 * C) return;
  const int plane = i / C, c = i % C;
  const float g = plane ? g_i[c] : g_r[c];
  const float bb = plane ? b_i[c] : b_r[c];
  const float s = rstd[i] * g;
  sc[i] = s;
  sh[i] = bb - mean[i] * s;
}

// ---------------------------------------------------------------------------
// Fused MFMA MLP v4: 128 px/block, 512 threads (8 waves), 160 KB LDS.
// Hidden chunk = 128 rows: GEMM1 wave w owns rows w*16 (no duplication),
// 6 chunks x 2 barriers = 12 barriers (was 24). GEMM2: (wr2,wc2) split, K=128.
// ---------------------------------------------------------------------------
template <bool PK>
__global__ __launch_bounds__(512) void k_mlp(
    float* __restrict__ outp,
    const float* __restrict__ w1_r, const float* __restrict__ w1_i,
    const float* __restrict__ w2_r, const float* __restrict__ w2_i,
    const short* __restrict__ wpk,
    const float* __restrict__ sc1, const float* __restrict__ sh1)
{
  __shared__ short sXm[2][128 * 192];  // 96 KB
  __shared__ short sH[2][128 * 128];   // 64 KB  [plane][px*128 + kb^s]

  const int t = threadIdx.x;
  const int pix0 = blockIdx.x * 128;
  const int b = pix0 >> 14;
  const int p0 = pix0 & (HW - 1);
  const float* yrp = outp;
  const float* yip = outp + PLANE;

  // stage bn1(y) tile: 192 c x 32 quads = 6144 float4-pairs
  #pragma unroll
  for (int it = 0; it < 12; ++it) {
    const int idx = t + it * 512;
    const int c = idx >> 5;
    const int q = (idx & 31) << 2;
    const size_t g = (size_t)(b * C + c) * HW + p0 + q;
    const float4 vr = *(const float4*)(yrp + g);
    const float4 vi = *(const float4*)(yip + g);
    const float srr = sc1[c], hrr = sh1[c];
    const float sii = sc1[C + c], hii = sh1[C + c];
    const float fr[4] = {vr.x * srr + hrr, vr.y * srr + hrr, vr.z * srr + hrr, vr.w * srr + hrr};
    const float fi[4] = {vi.x * sii + hii, vi.y * sii + hii, vi.z * sii + hii, vi.w * sii + hii};
    #pragma unroll
    for (int i2 = 0; i2 < 4; ++i2) {
      const int p = q + i2;
      const int s = (p & 7) << 3;
      sXm[0][p * 192 + (c ^ s)] = (short)f2bf(fr[i2]);
      sXm[1][p * 192 + (c ^ s)] = (short)f2bf(fi[i2]);
    }
  }
  __syncthreads();

  const int lane = t & 63;
  const int w = t >> 6;         // 0..7
  const int lr = lane & 15;
  const int lg = lane >> 4;
  const int wr2 = w >> 1;       // 0..3 GEMM2 row groups
  const int wc2 = w & 1;        // 0..1 GEMM2 px half

  f32x4 acc2r[3][4] = {};
  f32x4 acc2i[3][4] = {};

  for (int hc = 0; hc < 6; ++hc) {
    // ---- GEMM1: hidden rows [hc*128 + w*16, +16) x all 128 px, K=192 ----
    f32x4 hfr[8] = {}, hfi[8] = {};
    const int hrow = hc * 128 + w * 16 + lr;
    #pragma unroll
    for (int ks = 0; ks < 6; ++ks) {
      const int k8 = ks * 32 + lg * 8;
      bf16x8 a1r, a1i;
      if constexpr (PK) {
        a1r = *(const bf16x8*)(wpk + OW1_R + (size_t)hrow * C + k8);
        a1i = *(const bf16x8*)(wpk + OW1_I + (size_t)hrow * C + k8);
      } else {
        const float* w1rp = w1_r + (size_t)hrow * C;
        const float* w1ip = w1_i + (size_t)hrow * C;
        float a[8];
        *(float4*)&a[0] = *(const float4*)(w1rp + k8);
        *(float4*)&a[4] = *(const float4*)(w1rp + k8 + 4);
        a1r = pack8(a);
        *(float4*)&a[0] = *(const float4*)(w1ip + k8);
        *(float4*)&a[4] = *(const float4*)(w1ip + k8 + 4);
        a1i = pack8(a);
      }
      const bf16x8 a1in = negb(a1i);
      #pragma unroll
      for (int cb = 0; cb < 8; ++cb) {
        const int p = cb * 16 + lr;
        const int s = (p & 7) << 3;
        const bf16x8 br = *(const bf16x8*)&sXm[0][p * 192 + (k8 ^ s)];
        const bf16x8 bi = *(const bf16x8*)&sXm[1][p * 192 + (k8 ^ s)];
        hfr[cb] = __builtin_amdgcn_mfma_f32_16x16x32_bf16(a1r,  br, hfr[cb], 0, 0, 0);
        hfr[cb] = __builtin_amdgcn_mfma_f32_16x16x32_bf16(a1in, bi, hfr[cb], 0, 0, 0);
        hfi[cb] = __builtin_amdgcn_mfma_f32_16x16x32_bf16(a1r,  bi, hfi[cb], 0, 0, 0);
        hfi[cb] = __builtin_amdgcn_mfma_f32_16x16x32_bf16(a1i,  br, hfi[cb], 0, 0, 0);
      }
    }

    // ---- magnitude GELU (h * Phi(m), fast poly) ----
    float outr[8][4], outi[8][4];
    #pragma unroll
    for (int cb = 0; cb < 8; ++cb) {
      #pragma unroll
      for (int r = 0; r < 4; ++r) {
        const float re = hfr[cb][r], im = hfi[cb][r];
        const float f = phi_gelu(sqrtf(re * re + im * im));
        outr[cb][r] = re * f;
        outi[cb][r] = im * f;
      }
    }
    __syncthreads();   // previous chunk's GEMM2 reads complete
    #pragma unroll
    for (int cb = 0; cb < 8; ++cb) {
      const int p = cb * 16 + lr;
      const int s = (p & 7) << 3;
      const int kb = w * 16 + lg * 4;
      const int e = p * 128 + (kb ^ s);
      *(uint2*)&sH[0][e] = make_uint2(
          (unsigned)f2bf(outr[cb][0]) | ((unsigned)f2bf(outr[cb][1]) << 16),
          (unsigned)f2bf(outr[cb][2]) | ((unsigned)f2bf(outr[cb][3]) << 16));
      *(uint2*)&sH[1][e] = make_uint2(
          (unsigned)f2bf(outi[cb][0]) | ((unsigned)f2bf(outi[cb][1]) << 16),
          (unsigned)f2bf(outi[cb][2]) | ((unsigned)f2bf(outi[cb][3]) << 16));
    }
    __syncthreads();   // sH visible

    // ---- GEMM2: acc2 += W2[:, chunk] . Ht, K=128 ----
    #pragma unroll
    for (int ks2 = 0; ks2 < 4; ++ks2) {
      const int k8 = ks2 * 32 + lg * 8;
      bf16x8 br2[4], bi2[4];
      #pragma unroll
      for (int cb = 0; cb < 4; ++cb) {
        const int p = wc2 * 64 + cb * 16 + lr;
        const int s = (p & 7) << 3;
        br2[cb] = *(const bf16x8*)&sH[0][p * 128 + (k8 ^ s)];
        bi2[cb] = *(const bf16x8*)&sH[1][p * 128 + (k8 ^ s)];
      }
      #pragma unroll
      for (int ob = 0; ob < 3; ++ob) {
        const int row = (wr2 * 3 + ob) * 16 + lr;
        bf16x8 a2r, a2i;
        if constexpr (PK) {
          a2r = *(const bf16x8*)(wpk + OW2_R + (size_t)row * C4 + hc * 128 + k8);
          a2i = *(const bf16x8*)(wpk + OW2_I + (size_t)row * C4 + hc * 128 + k8);
        } else {
          const size_t wbase = (size_t)row * C4 + hc * 128 + k8;
          float a[8];
          *(float4*)&a[0] = *(const float4*)(w2_r + wbase);
          *(float4*)&a[4] = *(const float4*)(w2_r + wbase + 4);
          a2r = pack8(a);
          *(float4*)&a[0] = *(const float4*)(w2_i + wbase);
          *(float4*)&a[4] = *(const float4*)(w2_i + wbase + 4);
          a2i = pack8(a);
        }
        const bf16x8 a2in = negb(a2i);
        #pragma unroll
        for (int cb = 0; cb < 4; ++cb) {
          acc2r[ob][cb] = __builtin_amdgcn_mfma_f32_16x16x32_bf16(a2r,  br2[cb], acc2r[ob][cb], 0, 0, 0);
          acc2r[ob][cb] = __builtin_amdgcn_mfma_f32_16x16x32_bf16(a2in, bi2[cb], acc2r[ob][cb], 0, 0, 0);
          acc2i[ob][cb] = __builtin_amdgcn_mfma_f32_16x16x32_bf16(a2r,  bi2[cb], acc2i[ob][cb], 0, 0, 0);
          acc2i[ob][cb] = __builtin_amdgcn_mfma_f32_16x16x32_bf16(a2i,  br2[cb], acc2i[ob][cb], 0, 0, 0);
        }
      }
    }
  }

  // ---- epilogue: x2 = bn1(y) (from sXm, bf16) + acc2 ----
  #pragma unroll
  for (int ob = 0; ob < 3; ++ob) {
    #pragma unroll
    for (int cb = 0; cb < 4; ++cb) {
      const int pxl = wc2 * 64 + cb * 16 + lr;
      const int s = (pxl & 7) << 3;
      const int chb = (wr2 * 3 + ob) * 16 + lg * 4;
      const int ebase = pxl * 192 + (chb ^ s);
      const int px = p0 + pxl;
      #pragma unroll
      for (int r = 0; r < 4; ++r) {
        const int ch = chb + r;
        const size_t g = (size_t)(b * C + ch) * HW + px;
        outp[g] = bf2f(sXm[0][ebase + r]) + acc2r[ob][cb][r];
        outp[PLANE + g] = bf2f(sXm[1][ebase + r]) + acc2i[ob][cb][r];
      }
    }
  }
}

// In-place BN2 apply over d_out (both planes).
__global__ __launch_bounds__(256) void k_bnfinal(
    float* __restrict__ xo, const float* __restrict__ sc, const float* __restrict__ sh)
{
  const int total4 = (2 * PLANE) / 4;
  for (int i = blockIdx.x * blockDim.x + threadIdx.x; i < total4; i += gridDim.x * blockDim.x) {
    const int e = i * 4;
    const int plane = (e >= PLANE) ? 1 : 0;
    const int w = plane ? (e - PLANE) : e;
    const int ch = (w >> 14) % C;
    const float s = sc[plane * C + ch], hh = sh[plane * C + ch];
    float4 v = *(float4*)(xo + e);
    v.x = v.x * s + hh;
    v.y = v.y * s + hh;
    v.z = v.z * s + hh;
    v.w = v.w * s + hh;
    *(float4*)(xo + e) = v;
  }
}

}  // namespace

extern "C" void kernel_launch(void* const* d_in, const int* in_sizes, int n_in,
                              void* d_out, int out_size, void* d_ws, size_t ws_size,
                              hipStream_t stream)
{
  (void)in_sizes; (void)n_in; (void)out_size;
  const float* x_real  = (const float*)d_in[0];
  const float* x_imag  = (const float*)d_in[1];
  const float* qkv_wr  = (const float*)d_in[2];
  const float* qkv_wi  = (const float*)d_in[3];
  const float* proj_wr = (const float*)d_in[4];
  const float* proj_wi = (const float*)d_in[5];
  const float* rpb     = (const float*)d_in[6];
  const float* n1_gr   = (const float*)d_in[7];
  const float* n1_br   = (const float*)d_in[8];
  const float* n1_gi   = (const float*)d_in[9];
  const float* n1_bi   = (const float*)d_in[10];
  const float* mlp1_wr = (const float*)d_in[11];
  const float* mlp1_wi = (const float*)d_in[12];
  const float* mlp2_wr = (const float*)d_in[13];
  const float* mlp2_wi = (const float*)d_in[14];
  const float* n2_gr   = (const float*)d_in[15];
  const float* n2_br   = (const float*)d_in[16];
  const float* n2_gi   = (const float*)d_in[17];
  const float* n2_bi   = (const float*)d_in[18];

  const size_t pkBytes = (size_t)PK_TOTAL * 2;               // 1769472
  const size_t partBytes = (size_t)ZS * 2 * C * 2 * 8;       // 49152
  const bool pk = ws_size >= pkBytes + partBytes + 8192;

  float* outp = (float*)d_out;
  float* yr = outp;
  float* yi = outp + PLANE;

  if (pk) {
    short* wpk = (short*)d_ws;
    double* part = (double*)((char*)d_ws + pkBytes);
    float* st = (float*)((char*)d_ws + pkBytes + partBytes);
    float* sc1 = st;        float* sh1 = st + 384;
    float* sc2 = st + 768;  float* sh2 = st + 1152;

    k_pack<<<1024, 256, 0, stream>>>(qkv_wr, qkv_wi, proj_wr, proj_wi,
                                     mlp1_wr, mlp1_wi, mlp2_wr, mlp2_wi, wpk);
    k_attn<true><<<1024, 768, 0, stream>>>(x_real, x_imag, qkv_wr, qkv_wi,
                                           proj_wr, proj_wi, wpk, rpb, yr, yi);
    k_statsp<<<dim3(C, 2, ZS), 256, 0, stream>>>(yr, yi, part);
    k_bnpar2<<<2, 192, 0, stream>>>(part, n1_gr, n1_br, n1_gi, n1_bi, sc1, sh1);
    k_mlp<true><<<Bn * HW / 128, 512, 0, stream>>>(outp, mlp1_wr, mlp1_wi,
                                                   mlp2_wr, mlp2_wi, wpk, sc1, sh1);
    k_statsp<<<dim3(C, 2, ZS), 256, 0, stream>>>(outp, outp + PLANE, part);
    k_bnpar2<<<2, 192, 0, stream>>>(part, n2_gr, n2_br, n2_gi, n2_bi, sc2, sh2);
    k_bnfinal<<<2048, 256, 0, stream>>>(outp, sc2, sh2);
  } else {
    float* st = (float*)d_ws;
    float* mean1 = st;          float* rstd1 = st + 384;
    float* sc1   = st + 768;    float* sh1   = st + 1152;
    float* mean2 = st + 1536;   float* rstd2 = st + 1920;
    float* sc2   = st + 2304;   float* sh2   = st + 2688;

    k_attn<false><<<1024, 768, 0, stream>>>(x_real, x_imag, qkv_wr, qkv_wi,
                                            proj_wr, proj_wi, nullptr, rpb, yr, yi);
    k_stats<<<dim3(C, 2), 256, 0, stream>>>(yr, yi, mean1, rstd1);
    k_bnpar<<<2, 192, 0, stream>>>(mean1, rstd1, n1_gr, n1_br, n1_gi, n1_bi, sc1, sh1);
    k_mlp<false><<<Bn * HW / 128, 512, 0, stream>>>(outp, mlp1_wr, mlp1_wi,
                                                    mlp2_wr, mlp2_wi, nullptr, sc1, sh1);
    k_stats<<<dim3(C, 2), 256, 0, stream>>>(outp, outp + PLANE, mean2, rstd2);
    k_bnpar<<<2, 192, 0, stream>>>(mean2, rstd2, n2_gr, n2_br, n2_gi, n2_bi, sc2, sh2);
    k_bnfinal<<<2048, 256, 0, stream>>>(outp, sc2, sh2);
  }
}

// Round 11
// 512.701 us; speedup vs baseline: 1.0558x; 1.0558x over previous
//
#include <hip/hip_runtime.h>

namespace {

constexpr int Bn = 4;
constexpr int C  = 192;
constexpr int Wd = 128;
constexpr int HW = 16384;            // 128*128
constexpr int PLANE = Bn * C * HW;   // 12582912
constexpr int NH = 6;
constexpr int HD = 32;
constexpr int C4 = 4 * C;            // 768
constexpr float SCALE = 0.17677669529663687f;  // 32^-0.5

// packed bf16 weight layout in d_ws (short offsets)
constexpr int OQKV_R = 0;            // 576*192
constexpr int OQKV_I = 110592;
constexpr int OPROJ_R = 221184;      // 192*192
constexpr int OPROJ_I = 258048;
constexpr int OW1_R = 294912;        // 768*192
constexpr int OW1_I = 442368;
constexpr int OW2_R = 589824;        // 192*768
constexpr int OW2_I = 737280;
constexpr int PK_TOTAL = 884736;
constexpr int ZS = 8;                // stats split factor

typedef short bf16x8 __attribute__((ext_vector_type(8)));
typedef float f32x4 __attribute__((ext_vector_type(4)));

__device__ inline unsigned short f2bf(float f) {
  union { float f; unsigned u; } v; v.f = f;
  const unsigned r = v.u + 0x7FFFu + ((v.u >> 16) & 1u);
  return (unsigned short)(r >> 16);
}

__device__ inline float bf2f(short s) {
  union { unsigned u; float f; } v;
  v.u = ((unsigned)(unsigned short)s) << 16;
  return v.f;
}

__device__ inline bf16x8 pack8(const float* f) {
  union { bf16x8 v; unsigned short s[8]; } x;
#pragma unroll
  for (int j = 0; j < 8; ++j) x.s[j] = f2bf(f[j]);
  return x.v;
}

__device__ inline uint2 pack4(const f32x4 v) {
  return make_uint2((unsigned)f2bf(v[0]) | ((unsigned)f2bf(v[1]) << 16),
                    (unsigned)f2bf(v[2]) | ((unsigned)f2bf(v[3]) << 16));
}

__device__ inline bf16x8 negb(bf16x8 a) {
  union { bf16x8 v; unsigned u[4]; } x;
  x.v = a;
#pragma unroll
  for (int j = 0; j < 4; ++j) x.u[j] ^= 0x80008000u;
  return x.v;
}

// Phi(m) = 0.5(1+erf(m/sqrt2)), m>=0. Abramowitz-Stegun 7.1.26, |err|<1.5e-7.
__device__ inline float phi_gelu(float m) {
  const float x = m * 0.70710678f;
  const float tt = 1.0f / (1.0f + 0.3275911f * x);
  const float poly = tt * (0.254829592f + tt * (-0.284496736f +
                     tt * (1.421413741f + tt * (-1.453152027f + tt * 1.061405429f))));
  return 1.0f - 0.5f * poly * __expf(-x * x);
}

// ---------------------------------------------------------------------------
// Pack all weights to bf16 into ws (one pass, ~900K elements).
// ---------------------------------------------------------------------------
__global__ __launch_bounds__(256) void k_pack(
    const float* __restrict__ s0, const float* __restrict__ s1,
    const float* __restrict__ s2, const float* __restrict__ s3,
    const float* __restrict__ s4, const float* __restrict__ s5,
    const float* __restrict__ s6, const float* __restrict__ s7,
    short* __restrict__ dst)
{
  for (int i = blockIdx.x * 256 + threadIdx.x; i < PK_TOTAL; i += gridDim.x * 256) {
    const float* s; int off;
    if (i < OPROJ_R) {
      if (i < OQKV_I) { s = s0; off = i; } else { s = s1; off = i - OQKV_I; }
    } else if (i < OW1_R) {
      if (i < OPROJ_I) { s = s2; off = i - OPROJ_R; } else { s = s3; off = i - OPROJ_I; }
    } else if (i < OW2_R) {
      if (i < OW1_I) { s = s4; off = i - OW1_R; } else { s = s5; off = i - OW1_I; }
    } else {
      if (i < OW2_I) { s = s6; off = i - OW2_R; } else { s = s7; off = i - OW2_I; }
    }
    dst[i] = (short)f2bf(s[off]);
  }
}

// ---------------------------------------------------------------------------
// Stage 1 (MFMA): windowed complex attention + proj + residual -> y in d_out.
// Block = 2 windows (64 px), 768 threads (12 waves).
// R11: gather-staging (8 coalesced dword loads + one b128 LDS write/pair)
// to eliminate the 16-way transpose-store bank conflicts.
// ---------------------------------------------------------------------------
template <bool PK>
__global__ __launch_bounds__(768) void k_attn(
    const float* __restrict__ xr, const float* __restrict__ xi,
    const float* __restrict__ wqkv_r, const float* __restrict__ wqkv_i,
    const float* __restrict__ wp_r, const float* __restrict__ wp_i,
    const short* __restrict__ wpk,
    const float* __restrict__ rpb,
    float* __restrict__ yr, float* __restrict__ yi)
{
  __shared__ short sX[2][64 * 192];   // x window bf16 [px][c^s]
  __shared__ short sQ[2][64 * 64];    // q head-pair [px][cc^s]
  __shared__ short sK[2][64 * 64];    // k head-pair [px][cc^s]
  __shared__ short sV[2][64 * 64];    // v head-pair [cc][px^s]
  __shared__ short sAO[2][64 * 64];   // attn-out head-pair [px][cc^s]
  __shared__ short sAT[2][4][1024];   // attn weights per task [n][m^s]
  __shared__ float sB[640];           // rpb table

  const int t = threadIdx.x;
  const int b = blockIdx.x >> 8;
  const int rem = blockIdx.x & 255;
  const int r0 = (rem >> 4) << 3;
  const int c0 = (rem & 15) << 3;     // two 4-wide windows: c0, c0+4
  const int gbase = b * C * HW + r0 * Wd + c0;

  // ---- gather-stage x window as bf16: thread = (px, c8) pair ----
  #pragma unroll
  for (int it = 0; it < 2; ++it) {
    const int idx = t + it * 768;          // 0..1535
    const int p = idx & 63;                // px
    const int c8 = idx >> 6;               // 0..23
    const int wvs = p >> 5;
    const int row = (p & 31) >> 2;
    const int col = p & 3;
    const int goff = gbase + row * Wd + wvs * 4 + col;
    float fr[8], fi[8];
    #pragma unroll
    for (int j = 0; j < 8; ++j) {
      const size_t g = (size_t)goff + (size_t)(c8 * 8 + j) * HW;
      fr[j] = xr[g];
      fi[j] = xi[g];
    }
    const int s = (p & 7) << 3;
    const int e = p * 192 + ((c8 * 8) ^ s);
    *(bf16x8*)&sX[0][e] = pack8(fr);
    *(bf16x8*)&sX[1][e] = pack8(fi);
  }
  for (int i = t; i < 630; i += 768) sB[i] = rpb[i];
  __syncthreads();

  const int lane = t & 63;
  const int w = t >> 6;           // 0..11
  const int lr = lane & 15;
  const int lg = lane >> 4;

  f32x4 apr[4] = {}, api[4] = {};   // proj accumulators (persist; rows w*16)

  for (int g = 0; g < 3; ++g) {
    // ======== QKV GEMM: 192 rows (q64,k64,v64 of head pair) x 64 px ========
    {
      const int lrow = w * 16;             // 0..176
      const int sec = lrow >> 6;           // 0=q 1=k 2=v
      const int ccb = lrow & 63;
      const int R = sec * 192 + g * 64 + ccb + lr;
      f32x4 dr[4] = {}, di[4] = {};
      #pragma unroll
      for (int ks = 0; ks < 6; ++ks) {
        const int k8 = ks * 32 + lg * 8;
        bf16x8 ar, ai;
        if constexpr (PK) {
          ar = *(const bf16x8*)(wpk + OQKV_R + (size_t)R * C + k8);
          ai = *(const bf16x8*)(wpk + OQKV_I + (size_t)R * C + k8);
        } else {
          const float* wrp = wqkv_r + (size_t)R * C;
          const float* wip = wqkv_i + (size_t)R * C;
          float a[8];
          *(float4*)&a[0] = *(const float4*)(wrp + k8);
          *(float4*)&a[4] = *(const float4*)(wrp + k8 + 4);
          ar = pack8(a);
          *(float4*)&a[0] = *(const float4*)(wip + k8);
          *(float4*)&a[4] = *(const float4*)(wip + k8 + 4);
          ai = pack8(a);
        }
        const bf16x8 ain = negb(ai);
        #pragma unroll
        for (int cb = 0; cb < 4; ++cb) {
          const int px = cb * 16 + lr;
          const int s = (px & 7) << 3;
          const bf16x8 br = *(const bf16x8*)&sX[0][px * 192 + (k8 ^ s)];
          const bf16x8 bi = *(const bf16x8*)&sX[1][px * 192 + (k8 ^ s)];
          dr[cb] = __builtin_amdgcn_mfma_f32_16x16x32_bf16(ar,  br, dr[cb], 0, 0, 0);
          dr[cb] = __builtin_amdgcn_mfma_f32_16x16x32_bf16(ain, bi, dr[cb], 0, 0, 0);
          di[cb] = __builtin_amdgcn_mfma_f32_16x16x32_bf16(ar,  bi, di[cb], 0, 0, 0);
          di[cb] = __builtin_amdgcn_mfma_f32_16x16x32_bf16(ai,  br, di[cb], 0, 0, 0);
        }
      }
      if (sec < 2) {
        short* d0 = sec ? sK[0] : sQ[0];
        short* d1 = sec ? sK[1] : sQ[1];
        #pragma unroll
        for (int cb = 0; cb < 4; ++cb) {
          const int px = cb * 16 + lr;
          const int e = px * 64 + ((ccb + lg * 4) ^ ((px & 7) << 3));
          *(uint2*)&d0[e] = pack4(dr[cb]);
          *(uint2*)&d1[e] = pack4(di[cb]);
        }
      } else {
        #pragma unroll
        for (int cb = 0; cb < 4; ++cb) {
          const int px = cb * 16 + lr;
          #pragma unroll
          for (int r = 0; r < 4; ++r) {
            const int dd = ccb + lg * 4 + r;
            const int e = dd * 64 + (px ^ ((dd & 7) << 3));
            sV[0][e] = (short)f2bf(dr[cb][r]);
            sV[1][e] = (short)f2bf(di[cb][r]);
          }
        }
      }
    }
    __syncthreads();   // bar A: qkv visible

    // ======== attention: waves 0..7 = (task, half); waves 8..11 idle ========
    if (w < 8) {
      const int task = w >> 1;
      const int half = w & 1;
      const int hloc = task >> 1;
      const int wv = task & 1;
      const int ccq = hloc * 32;
      const int h = 2 * g + hloc;
      bf16x8 aqr, aqi, bkr[2], bki[2];
      {
        const int pxq = wv * 32 + half * 16 + lr;
        const int eq = pxq * 64 + ((ccq + lg * 8) ^ ((pxq & 7) << 3));
        aqr = *(const bf16x8*)&sQ[0][eq];
        aqi = *(const bf16x8*)&sQ[1][eq];
      }
      #pragma unroll
      for (int j = 0; j < 2; ++j) {
        const int pxk = wv * 32 + j * 16 + lr;
        const int ek = pxk * 64 + ((ccq + lg * 8) ^ ((pxk & 7) << 3));
        bkr[j] = *(const bf16x8*)&sK[0][ek];
        bki[j] = *(const bf16x8*)&sK[1][ek];
      }
      f32x4 sre[2], sim[2];
      #pragma unroll
      for (int j = 0; j < 2; ++j) {
        f32x4 z = {};
        f32x4 re = __builtin_amdgcn_mfma_f32_16x16x32_bf16(aqr, bkr[j], z, 0, 0, 0);
        re = __builtin_amdgcn_mfma_f32_16x16x32_bf16(aqi, bki[j], re, 0, 0, 0);
        f32x4 im = __builtin_amdgcn_mfma_f32_16x16x32_bf16(aqi, bkr[j], z, 0, 0, 0);
        im = __builtin_amdgcn_mfma_f32_16x16x32_bf16(negb(aqr), bki[j], im, 0, 0, 0);
        sre[j] = re;
        sim[j] = im;
      }
      float re_[2][4], im_[2][4], mg_[2][4];
      #pragma unroll
      for (int j = 0; j < 2; ++j) {
        const int m = j * 16 + lr;
        #pragma unroll
        for (int r = 0; r < 4; ++r) {
          const int n = half * 16 + lg * 4 + r;
          const int bidx = ((n >> 2) - (m >> 2) + 7) * 7 + ((n & 3) - (m & 3) + 3);
          const float re = sre[j][r] * SCALE + sB[bidx * NH + h];
          const float im = sim[j][r] * SCALE;
          re_[j][r] = re;
          im_[j][r] = im;
          mg_[j][r] = sqrtf(re * re + im * im);
        }
      }
      #pragma unroll
      for (int r = 0; r < 4; ++r) {
        float mx = fmaxf(mg_[0][r], mg_[1][r]);
        mx = fmaxf(mx, __shfl_xor(mx, 1));
        mx = fmaxf(mx, __shfl_xor(mx, 2));
        mx = fmaxf(mx, __shfl_xor(mx, 4));
        mx = fmaxf(mx, __shfl_xor(mx, 8));
        const float e0 = expf(mg_[0][r] - mx);
        const float e1 = expf(mg_[1][r] - mx);
        float se = e0 + e1;
        se += __shfl_xor(se, 1);
        se += __shfl_xor(se, 2);
        se += __shfl_xor(se, 4);
        se += __shfl_xor(se, 8);
        const float inv = 1.f / se;
        const float f0 = e0 * inv / (mg_[0][r] + 1e-8f);
        const float f1 = e1 * inv / (mg_[1][r] + 1e-8f);
        const int n = half * 16 + lg * 4 + r;
        const int sw = (n & 3) << 3;
        sAT[0][task][n * 32 + (lr ^ sw)]        = (short)f2bf(re_[0][r] * f0);
        sAT[1][task][n * 32 + (lr ^ sw)]        = (short)f2bf(im_[0][r] * f0);
        sAT[0][task][n * 32 + ((16 + lr) ^ sw)] = (short)f2bf(re_[1][r] * f1);
        sAT[1][task][n * 32 + ((16 + lr) ^ sw)] = (short)f2bf(im_[1][r] * f1);
      }
      bf16x8 bar_, bai_;
      {
        const int n = half * 16 + lr;
        const int e = n * 32 + ((lg * 8) ^ ((n & 3) << 3));
        bar_ = *(const bf16x8*)&sAT[0][task][e];
        bai_ = *(const bf16x8*)&sAT[1][task][e];
      }
      #pragma unroll
      for (int i2 = 0; i2 < 2; ++i2) {
        const int dd = ccq + i2 * 16 + lr;
        const int e = dd * 64 + ((wv * 32 + lg * 8) ^ ((dd & 7) << 3));
        const bf16x8 avr = *(const bf16x8*)&sV[0][e];
        const bf16x8 avi = *(const bf16x8*)&sV[1][e];
        const bf16x8 avin = negb(avi);
        f32x4 z = {};
        f32x4 pr = __builtin_amdgcn_mfma_f32_16x16x32_bf16(avr, bar_, z, 0, 0, 0);
        pr = __builtin_amdgcn_mfma_f32_16x16x32_bf16(avin, bai_, pr, 0, 0, 0);
        f32x4 pi = __builtin_amdgcn_mfma_f32_16x16x32_bf16(avr, bai_, z, 0, 0, 0);
        pi = __builtin_amdgcn_mfma_f32_16x16x32_bf16(avi, bar_, pi, 0, 0, 0);
        const int px = wv * 32 + half * 16 + lr;
        const int e2 = px * 64 + ((ccq + i2 * 16 + lg * 4) ^ ((px & 7) << 3));
        *(uint2*)&sAO[0][e2] = pack4(pr);
        *(uint2*)&sAO[1][e2] = pack4(pi);
      }
    }

    // prefetch proj A-frags so their latency lands in bar B's drain (PK path)
    const int o = w * 16 + lr;
    bf16x8 ppr[2], ppi[2];
    if constexpr (PK) {
      #pragma unroll
      for (int ks = 0; ks < 2; ++ks) {
        const int k8 = ks * 32 + lg * 8;
        ppr[ks] = *(const bf16x8*)(wpk + OPROJ_R + (size_t)o * C + g * 64 + k8);
        ppi[ks] = *(const bf16x8*)(wpk + OPROJ_I + (size_t)o * C + g * 64 + k8);
      }
    }
    __syncthreads();   // bar B: attn-out visible

    // ======== proj accumulation: K = 64 (head pair), rows w*16 ========
    #pragma unroll
    for (int ks = 0; ks < 2; ++ks) {
      const int k8 = ks * 32 + lg * 8;
      bf16x8 pbr[4], pbi[4];
      #pragma unroll
      for (int cb = 0; cb < 4; ++cb) {
        const int px = cb * 16 + lr;
        const int e = px * 64 + (k8 ^ ((px & 7) << 3));
        pbr[cb] = *(const bf16x8*)&sAO[0][e];
        pbi[cb] = *(const bf16x8*)&sAO[1][e];
      }
      bf16x8 ar, ai;
      if constexpr (PK) {
        ar = ppr[ks];
        ai = ppi[ks];
      } else {
        const size_t wb = (size_t)o * C + g * 64 + k8;
        float a[8];
        *(float4*)&a[0] = *(const float4*)(wp_r + wb);
        *(float4*)&a[4] = *(const float4*)(wp_r + wb + 4);
        ar = pack8(a);
        *(float4*)&a[0] = *(const float4*)(wp_i + wb);
        *(float4*)&a[4] = *(const float4*)(wp_i + wb + 4);
        ai = pack8(a);
      }
      const bf16x8 ain = negb(ai);
      #pragma unroll
      for (int cb = 0; cb < 4; ++cb) {
        apr[cb] = __builtin_amdgcn_mfma_f32_16x16x32_bf16(ar,  pbr[cb], apr[cb], 0, 0, 0);
        apr[cb] = __builtin_amdgcn_mfma_f32_16x16x32_bf16(ain, pbi[cb], apr[cb], 0, 0, 0);
        api[cb] = __builtin_amdgcn_mfma_f32_16x16x32_bf16(ar,  pbi[cb], api[cb], 0, 0, 0);
        api[cb] = __builtin_amdgcn_mfma_f32_16x16x32_bf16(ai,  pbr[cb], api[cb], 0, 0, 0);
      }
    }
  }

  // ======== epilogue: y = x + proj_out (residual from sX, bf16) ========
  #pragma unroll
  for (int cb = 0; cb < 4; ++cb) {
    const int px = cb * 16 + lr;
    const int n = px & 31;
    const int off0 = gbase + (n >> 2) * Wd + (px >> 5) * 4 + (n & 3);
    const int s = (px & 7) << 3;
    #pragma unroll
    for (int r = 0; r < 4; ++r) {
      const int c = w * 16 + lg * 4 + r;
      const size_t gg = (size_t)off0 + (size_t)c * HW;
      yr[gg] = bf2f(sX[0][px * 192 + (c ^ s)]) + apr[cb][r];
      yi[gg] = bf2f(sX[1][px * 192 + (c ^ s)]) + api[cb][r];
    }
  }
}

// ---------------------------------------------------------------------------
// Split BN stats: grid (C, 2, ZS). Deterministic partials (no atomics).
// ---------------------------------------------------------------------------
__global__ __launch_bounds__(256) void k_statsp(
    const float* __restrict__ src_r, const float* __restrict__ src_i,
    double* __restrict__ part)
{
  const int c = blockIdx.x;
  const int plane = blockIdx.y;
  const int z = blockIdx.z;
  const float* src = plane ? src_i : src_r;
  const int t = threadIdx.x;
  double s = 0.0, s2 = 0.0;
  for (int b = 0; b < Bn; ++b) {
    const float* p = src + (size_t)(b * C + c) * HW + (size_t)z * (HW / ZS);
    #pragma unroll
    for (int it = 0; it < 2; ++it) {
      const float4 v = *(const float4*)(p + t * 4 + it * 1024);
      s += (double)v.x + (double)v.y + (double)v.z + (double)v.w;
      s2 += (double)v.x * v.x + (double)v.y * v.y +
            (double)v.z * v.z + (double)v.w * v.w;
    }
  }
  __shared__ double ls[256], ls2[256];
  ls[t] = s; ls2[t] = s2;
  __syncthreads();
  for (int off = 128; off > 0; off >>= 1) {
    if (t < off) { ls[t] += ls[t + off]; ls2[t] += ls2[t + off]; }
    __syncthreads();
  }
  if (t == 0) {
    const int e = ((z * 2 + plane) * C + c) * 2;
    part[e] = ls[0];
    part[e + 1] = ls2[0];
  }
}

// Reduce partials -> folded BN scale/shift. grid 2 x 192.
__global__ void k_bnpar2(const double* __restrict__ part,
                         const float* __restrict__ g_r, const float* __restrict__ b_r,
                         const float* __restrict__ g_i, const float* __restrict__ b_i,
                         float* __restrict__ sc, float* __restrict__ sh)
{
  const int plane = blockIdx.x;
  const int c = threadIdx.x;
  double s = 0.0, s2 = 0.0;
  #pragma unroll
  for (int z = 0; z < ZS; ++z) {
    const int e = ((z * 2 + plane) * C + c) * 2;
    s += part[e];
    s2 += part[e + 1];
  }
  const double inv = 1.0 / (double)(Bn * HW);
  const double m = s * inv;
  const double var = s2 * inv - m * m;
  const double rstd = 1.0 / sqrt(var + 1e-5);
  const float g = plane ? g_i[c] : g_r[c];
  const float bb = plane ? b_i[c] : b_r[c];
  const float sf = (float)(rstd) * g;
  sc[plane * C + c] = sf;
  sh[plane * C + c] = bb - (float)m * sf;
}

// ---------------------------------------------------------------------------
// Legacy monolithic stats (fallback when ws too small for partials).
// ---------------------------------------------------------------------------
__global__ __launch_bounds__(256) void k_stats(
    const float* __restrict__ src_r, const float* __restrict__ src_i,
    float* __restrict__ mean, float* __restrict__ rstd)
{
  const int c = blockIdx.x;
  const int plane = blockIdx.y;
  const float* src = plane ? src_i : src_r;
  const int t = threadIdx.x;
  double s = 0.0, s2 = 0.0;
  for (int b = 0; b < Bn; ++b) {
    const float* p = src + (size_t)(b * C + c) * HW;
    for (int i = t; i < HW; i += 256) {
      const double v = (double)p[i];
      s += v;
      s2 += v * v;
    }
  }
  __shared__ double ls[256], ls2[256];
  ls[t] = s; ls2[t] = s2;
  __syncthreads();
  for (int off = 128; off > 0; off >>= 1) {
    if (t < off) { ls[t] += ls[t + off]; ls2[t] += ls2[t + off]; }
    __syncthreads();
  }
  if (t == 0) {
    const double inv = 1.0 / (double)(Bn * HW);
    const double m = ls[0] * inv;
    const double var = ls2[0] * inv - m * m;
    mean[plane * C + c] = (float)m;
    rstd[plane * C + c] = (float)(1.0 / sqrt(var + 1e-5));
  }
}

__global__ void k_bnpar(const float* __restrict__ mean, const float* __restrict__ rstd,
                        const float* __restrict__ g_r, const float* __restrict__ b_r,
                        const float* __restrict__ g_i, const float* __restrict__ b_i,
                        float* __restrict__ sc, float* __restrict__ sh)
{
  const int i = blockIdx.x * blockDim.x + threadIdx.x;
  if (i >= 2 * C) return;
  const int plane = i / C, c = i % C;
  const float g = plane ? g_i[c] : g_r[c];
  const float bb = plane ? b_i[c] : b_r[c];
  const float s = rstd[i] * g;
  sc[i] = s;
  sh[i] = bb - mean[i] * s;
}

// ---------------------------------------------------------------------------
// Fused MFMA MLP (R9 structure, 128 px/block, chunk=64, 128 KB LDS) with
// R11 gather-staging (conflict-free transpose store).
// ---------------------------------------------------------------------------
template <bool PK>
__global__ __launch_bounds__(512) void k_mlp(
    float* __restrict__ outp,
    const float* __restrict__ w1_r, const float* __restrict__ w1_i,
    const float* __restrict__ w2_r, const float* __restrict__ w2_i,
    const short* __restrict__ wpk,
    const float* __restrict__ sc1, const float* __restrict__ sh1)
{
  __shared__ short sXm[2][128 * 192];  // 96 KB
  __shared__ short sH[2][128 * 64];    // 32 KB  [plane][px*64 + kb^s]

  const int t = threadIdx.x;
  const int pix0 = blockIdx.x * 128;
  const int b = pix0 >> 14;
  const int p0 = pix0 & (HW - 1);
  const float* yrp = outp;
  const float* yip = outp + PLANE;

  // ---- gather-stage bn1(y): thread = (px, c8) pair, conflict-free ----
  #pragma unroll
  for (int it = 0; it < 6; ++it) {
    const int idx = t + it * 512;        // 0..3071
    const int p = idx & 127;
    const int c8 = idx >> 7;             // 0..23
    float scr[8], shr[8], sci[8], shi[8];
    *(float4*)&scr[0] = *(const float4*)(sc1 + c8 * 8);
    *(float4*)&scr[4] = *(const float4*)(sc1 + c8 * 8 + 4);
    *(float4*)&shr[0] = *(const float4*)(sh1 + c8 * 8);
    *(float4*)&shr[4] = *(const float4*)(sh1 + c8 * 8 + 4);
    *(float4*)&sci[0] = *(const float4*)(sc1 + C + c8 * 8);
    *(float4*)&sci[4] = *(const float4*)(sc1 + C + c8 * 8 + 4);
    *(float4*)&shi[0] = *(const float4*)(sh1 + C + c8 * 8);
    *(float4*)&shi[4] = *(const float4*)(sh1 + C + c8 * 8 + 4);
    float fr[8], fi[8];
    #pragma unroll
    for (int j = 0; j < 8; ++j) {
      const size_t g = (size_t)(b * C + c8 * 8 + j) * HW + p0 + p;
      fr[j] = yrp[g] * scr[j] + shr[j];
      fi[j] = yip[g] * sci[j] + shi[j];
    }
    const int s = (p & 7) << 3;
    const int e = p * 192 + ((c8 * 8) ^ s);
    *(bf16x8*)&sXm[0][e] = pack8(fr);
    *(bf16x8*)&sXm[1][e] = pack8(fi);
  }
  __syncthreads();

  const int lane = t & 63;
  const int w = t >> 6;         // 0..7
  const int lr = lane & 15;
  const int lg = lane >> 4;
  const int wr = w >> 1;        // 0..3 row tiles
  const int wc = w & 1;         // 0..1 px half (64 px each)

  f32x4 acc2r[3][4] = {};
  f32x4 acc2i[3][4] = {};

  for (int hc = 0; hc < 12; ++hc) {
    // ---- GEMM1: h rows [hc*64 + wr*16, +16) x 64 px (wc half), K=192 ----
    f32x4 hfr[4] = {}, hfi[4] = {};
    #pragma unroll
    for (int ks = 0; ks < 6; ++ks) {
      const int k8 = ks * 32 + lg * 8;
      bf16x8 a1r, a1i;
      if constexpr (PK) {
        a1r = *(const bf16x8*)(wpk + OW1_R + (size_t)(hc * 64 + wr * 16 + lr) * C + k8);
        a1i = *(const bf16x8*)(wpk + OW1_I + (size_t)(hc * 64 + wr * 16 + lr) * C + k8);
      } else {
        const float* w1rp = w1_r + (size_t)(hc * 64 + wr * 16 + lr) * C;
        const float* w1ip = w1_i + (size_t)(hc * 64 + wr * 16 + lr) * C;
        float a[8];
        *(float4*)&a[0] = *(const float4*)(w1rp + k8);
        *(float4*)&a[4] = *(const float4*)(w1rp + k8 + 4);
        a1r = pack8(a);
        *(float4*)&a[0] = *(const float4*)(w1ip + k8);
        *(float4*)&a[4] = *(const float4*)(w1ip + k8 + 4);
        a1i = pack8(a);
      }
      const bf16x8 a1in = negb(a1i);
      #pragma unroll
      for (int cb = 0; cb < 4; ++cb) {
        const int p = wc * 64 + cb * 16 + lr;
        const int s = (p & 7) << 3;
        const bf16x8 br = *(const bf16x8*)&sXm[0][p * 192 + (k8 ^ s)];
        const bf16x8 bi = *(const bf16x8*)&sXm[1][p * 192 + (k8 ^ s)];
        hfr[cb] = __builtin_amdgcn_mfma_f32_16x16x32_bf16(a1r,  br, hfr[cb], 0, 0, 0);
        hfr[cb] = __builtin_amdgcn_mfma_f32_16x16x32_bf16(a1in, bi, hfr[cb], 0, 0, 0);
        hfi[cb] = __builtin_amdgcn_mfma_f32_16x16x32_bf16(a1r,  bi, hfi[cb], 0, 0, 0);
        hfi[cb] = __builtin_amdgcn_mfma_f32_16x16x32_bf16(a1i,  br, hfi[cb], 0, 0, 0);
      }
    }

    // ---- magnitude GELU (h * Phi(m), fast poly) ----
    float outr[4][4], outi[4][4];
    #pragma unroll
    for (int cb = 0; cb < 4; ++cb) {
      #pragma unroll
      for (int r = 0; r < 4; ++r) {
        const float re = hfr[cb][r], im = hfi[cb][r];
        const float f = phi_gelu(sqrtf(re * re + im * im));
        outr[cb][r] = re * f;
        outi[cb][r] = im * f;
      }
    }
    __syncthreads();   // previous chunk's GEMM2 reads complete
    #pragma unroll
    for (int cb = 0; cb < 4; ++cb) {
      const int p = wc * 64 + cb * 16 + lr;
      const int s = (p & 7) << 3;
      const int kb = wr * 16 + lg * 4;
      const int e = p * 64 + (kb ^ s);
      *(uint2*)&sH[0][e] = make_uint2(
          (unsigned)f2bf(outr[cb][0]) | ((unsigned)f2bf(outr[cb][1]) << 16),
          (unsigned)f2bf(outr[cb][2]) | ((unsigned)f2bf(outr[cb][3]) << 16));
      *(uint2*)&sH[1][e] = make_uint2(
          (unsigned)f2bf(outi[cb][0]) | ((unsigned)f2bf(outi[cb][1]) << 16),
          (unsigned)f2bf(outi[cb][2]) | ((unsigned)f2bf(outi[cb][3]) << 16));
    }
    __syncthreads();   // sH visible

    // ---- GEMM2: acc2 += W2[:, chunk] . Ht, K=64 ----
    #pragma unroll
    for (int ks2 = 0; ks2 < 2; ++ks2) {
      const int k8 = ks2 * 32 + lg * 8;
      bf16x8 br2[4], bi2[4];
      #pragma unroll
      for (int cb = 0; cb < 4; ++cb) {
        const int p = wc * 64 + cb * 16 + lr;
        const int s = (p & 7) << 3;
        br2[cb] = *(const bf16x8*)&sH[0][p * 64 + (k8 ^ s)];
        bi2[cb] = *(const bf16x8*)&sH[1][p * 64 + (k8 ^ s)];
      }
      #pragma unroll
      for (int ob = 0; ob < 3; ++ob) {
        const int row = (wr * 3 + ob) * 16 + lr;
        bf16x8 a2r, a2i;
        if constexpr (PK) {
          a2r = *(const bf16x8*)(wpk + OW2_R + (size_t)row * C4 + hc * 64 + k8);
          a2i = *(const bf16x8*)(wpk + OW2_I + (size_t)row * C4 + hc * 64 + k8);
        } else {
          const size_t wbase = (size_t)row * C4 + hc * 64 + k8;
          float a[8];
          *(float4*)&a[0] = *(const float4*)(w2_r + wbase);
          *(float4*)&a[4] = *(const float4*)(w2_r + wbase + 4);
          a2r = pack8(a);
          *(float4*)&a[0] = *(const float4*)(w2_i + wbase);
          *(float4*)&a[4] = *(const float4*)(w2_i + wbase + 4);
          a2i = pack8(a);
        }
        const bf16x8 a2in = negb(a2i);
        #pragma unroll
        for (int cb = 0; cb < 4; ++cb) {
          acc2r[ob][cb] = __builtin_amdgcn_mfma_f32_16x16x32_bf16(a2r,  br2[cb], acc2r[ob][cb], 0, 0, 0);
          acc2r[ob][cb] = __builtin_amdgcn_mfma_f32_16x16x32_bf16(a2in, bi2[cb], acc2r[ob][cb], 0, 0, 0);
          acc2i[ob][cb] = __builtin_amdgcn_mfma_f32_16x16x32_bf16(a2r,  bi2[cb], acc2i[ob][cb], 0, 0, 0);
          acc2i[ob][cb] = __builtin_amdgcn_mfma_f32_16x16x32_bf16(a2i,  br2[cb], acc2i[ob][cb], 0, 0, 0);
        }
      }
    }
  }

  // ---- epilogue: x2 = bn1(y) (from sXm, bf16) + acc2 ----
  #pragma unroll
  for (int ob = 0; ob < 3; ++ob) {
    #pragma unroll
    for (int cb = 0; cb < 4; ++cb) {
      const int pxl = wc * 64 + cb * 16 + lr;
      const int s = (pxl & 7) << 3;
      const int chb = (wr * 3 + ob) * 16 + lg * 4;
      const int ebase = pxl * 192 + (chb ^ s);
      const int px = p0 + pxl;
      #pragma unroll
      for (int r = 0; r < 4; ++r) {
        const int ch = chb + r;
        const size_t g = (size_t)(b * C + ch) * HW + px;
        outp[g] = bf2f(sXm[0][ebase + r]) + acc2r[ob][cb][r];
        outp[PLANE + g] = bf2f(sXm[1][ebase + r]) + acc2i[ob][cb][r];
      }
    }
  }
}

// In-place BN2 apply over d_out (both planes).
__global__ __launch_bounds__(256) void k_bnfinal(
    float* __restrict__ xo, const float* __restrict__ sc, const float* __restrict__ sh)
{
  const int total4 = (2 * PLANE) / 4;
  for (int i = blockIdx.x * blockDim.x + threadIdx.x; i < total4; i += gridDim.x * blockDim.x) {
    const int e = i * 4;
    const int plane = (e >= PLANE) ? 1 : 0;
    const int w = plane ? (e - PLANE) : e;
    const int ch = (w >> 14) % C;
    const float s = sc[plane * C + ch], hh = sh[plane * C + ch];
    float4 v = *(float4*)(xo + e);
    v.x = v.x * s + hh;
    v.y = v.y * s + hh;
    v.z = v.z * s + hh;
    v.w = v.w * s + hh;
    *(float4*)(xo + e) = v;
  }
}

}  // namespace

extern "C" void kernel_launch(void* const* d_in, const int* in_sizes, int n_in,
                              void* d_out, int out_size, void* d_ws, size_t ws_size,
                              hipStream_t stream)
{
  (void)in_sizes; (void)n_in; (void)out_size;
  const float* x_real  = (const float*)d_in[0];
  const float* x_imag  = (const float*)d_in[1];
  const float* qkv_wr  = (const float*)d_in[2];
  const float* qkv_wi  = (const float*)d_in[3];
  const float* proj_wr = (const float*)d_in[4];
  const float* proj_wi = (const float*)d_in[5];
  const float* rpb     = (const float*)d_in[6];
  const float* n1_gr   = (const float*)d_in[7];
  const float* n1_br   = (const float*)d_in[8];
  const float* n1_gi   = (const float*)d_in[9];
  const float* n1_bi   = (const float*)d_in[10];
  const float* mlp1_wr = (const float*)d_in[11];
  const float* mlp1_wi = (const float*)d_in[12];
  const float* mlp2_wr = (const float*)d_in[13];
  const float* mlp2_wi = (const float*)d_in[14];
  const float* n2_gr   = (const float*)d_in[15];
  const float* n2_br   = (const float*)d_in[16];
  const float* n2_gi   = (const float*)d_in[17];
  const float* n2_bi   = (const float*)d_in[18];

  const size_t pkBytes = (size_t)PK_TOTAL * 2;               // 1769472
  const size_t partBytes = (size_t)ZS * 2 * C * 2 * 8;       // 49152
  const bool pk = ws_size >= pkBytes + partBytes + 8192;

  float* outp = (float*)d_out;
  float* yr = outp;
  float* yi = outp + PLANE;

  if (pk) {
    short* wpk = (short*)d_ws;
    double* part = (double*)((char*)d_ws + pkBytes);
    float* st = (float*)((char*)d_ws + pkBytes + partBytes);
    float* sc1 = st;        float* sh1 = st + 384;
    float* sc2 = st + 768;  float* sh2 = st + 1152;

    k_pack<<<1024, 256, 0, stream>>>(qkv_wr, qkv_wi, proj_wr, proj_wi,
                                     mlp1_wr, mlp1_wi, mlp2_wr, mlp2_wi, wpk);
    k_attn<true><<<1024, 768, 0, stream>>>(x_real, x_imag, qkv_wr, qkv_wi,
                                           proj_wr, proj_wi, wpk, rpb, yr, yi);
    k_statsp<<<dim3(C, 2, ZS), 256, 0, stream>>>(yr, yi, part);
    k_bnpar2<<<2, 192, 0, stream>>>(part, n1_gr, n1_br, n1_gi, n1_bi, sc1, sh1);
    k_mlp<true><<<Bn * HW / 128, 512, 0, stream>>>(outp, mlp1_wr, mlp1_wi,
                                                   mlp2_wr, mlp2_wi, wpk, sc1, sh1);
    k_statsp<<<dim3(C, 2, ZS), 256, 0, stream>>>(outp, outp + PLANE, part);
    k_bnpar2<<<2, 192, 0, stream>>>(part, n2_gr, n2_br, n2_gi, n2_bi, sc2, sh2);
    k_bnfinal<<<2048, 256, 0, stream>>>(outp, sc2, sh2);
  } else {
    float* st = (float*)d_ws;
    float* mean1 = st;          float* rstd1 = st + 384;
    float* sc1   = st + 768;    float* sh1   = st + 1152;
    float* mean2 = st + 1536;   float* rstd2 = st + 1920;
    float* sc2   = st + 2304;   float* sh2   = st + 2688;

    k_attn<false><<<1024, 768, 0, stream>>>(x_real, x_imag, qkv_wr, qkv_wi,
                                            proj_wr, proj_wi, nullptr, rpb, yr, yi);
    k_stats<<<dim3(C, 2), 256, 0, stream>>>(yr, yi, mean1, rstd1);
    k_bnpar<<<2, 192, 0, stream>>>(mean1, rstd1, n1_gr, n1_br, n1_gi, n1_bi, sc1, sh1);
    k_mlp<false><<<Bn * HW / 128, 512, 0, stream>>>(outp, mlp1_wr, mlp1_wi,
                                                    mlp2_wr, mlp2_wi, nullptr, sc1, sh1);
    k_stats<<<dim3(C, 2), 256, 0, stream>>>(outp, outp + PLANE, mean2, rstd2);
    k_bnpar<<<2, 192, 0, stream>>>(mean2, rstd2, n2_gr, n2_br, n2_gi, n2_bi, sc2, sh2);
    k_bnfinal<<<2048, 256, 0, stream>>>(outp, sc2, sh2);
  }
}